// Round 1
// baseline (142.257 us; speedup 1.0000x reference)
//
#include <hip/hip_runtime.h>

// Fused Haar DWT (2x2) + 2x bilinear upsample (jax.image.resize half-pixel
// convention == clamped stencil: out[2k]=.25 t[k-1]+.75 t[k], out[2k+1]=.75 t[k]+.25 t[k+1]).
//
// Input  x: [8][64][256][256] f32
// Output: up(ll) [8][64][256][256], then concat([up(lh),up(hl),up(hh)],axis=1) [8][192][256][256]
//
// One block = one 64x64 output tile of one (n,c) plane.
// Step 1: build 34x34 subband halo tiles in LDS (68x68 input patch, float2 loads).
// Step 2: each thread writes 4 float4 rows-of-4 per subband (coalesced 16B stores).

__global__ __launch_bounds__(256) void haar_dwt_up_kernel(
    const float* __restrict__ x, float* __restrict__ out)
{
  const int plane = blockIdx.y;       // n*64 + c, 0..511
  const int ty = blockIdx.x >> 2;     // 4x4 tiles of 64x64
  const int tx = blockIdx.x & 3;
  const int tid = threadIdx.x;

  __shared__ float sLL[34][36];
  __shared__ float sLH[34][36];
  __shared__ float sHL[34][36];
  __shared__ float sHH[34][36];

  const float* __restrict__ xp = x + (size_t)plane * 65536u;
  const int kY0 = ty * 32 - 1;        // subband-space tile origin (with -1 halo)
  const int kX0 = tx * 32 - 1;

  // ---- Step 1: subband tiles into LDS ----
  for (int cidx = tid; cidx < 34 * 34; cidx += 256) {
    const int i  = cidx / 34;
    const int jj = cidx - i * 34;
    int k = kY0 + i;  k = k < 0 ? 0 : (k > 127 ? 127 : k);
    int j = kX0 + jj; j = j < 0 ? 0 : (j > 127 ? 127 : j);
    const float2 r0 = *reinterpret_cast<const float2*>(xp + (size_t)(2 * k) * 256 + 2 * j);
    const float2 r1 = *reinterpret_cast<const float2*>(xp + (size_t)(2 * k + 1) * 256 + 2 * j);
    const float a = r0.x, b = r0.y, c = r1.x, d = r1.y;
    sLL[i][jj] = 0.5f * (a + b + c + d);
    sLH[i][jj] = 0.5f * (c + d - a - b);
    sHL[i][jj] = 0.5f * (b + d - a - c);
    sHH[i][jj] = 0.5f * (a + d - b - c);
  }
  __syncthreads();

  // ---- Step 2: bilinear 2x upsample from LDS, 4 subbands ----
  const int n = plane >> 6;
  const int c = plane & 63;
  float* __restrict__ oLL = out + (size_t)plane * 65536u;
  float* __restrict__ oLH = out + 33554432u + (size_t)(n * 192 + c) * 65536u;
  float* __restrict__ oHL = oLH + (size_t)64 * 65536u;
  float* __restrict__ oHH = oLH + (size_t)128 * 65536u;

#pragma unroll
  for (int it = 0; it < 4; ++it) {
    const int p    = tid + it * 256;     // 0..1023 float4 slots in 64x64 tile
    const int orow = p >> 4;             // 16 float4s per output row
    const int m    = p & 15;
    const int li   = (orow >> 1) + 1;    // local subband row (halo offset +1)
    const int ry   = orow & 1;
    const int rA   = ry ? li     : li - 1;
    const int rB   = ry ? li + 1 : li;
    const float wA = ry ? 0.75f : 0.25f;
    const float wB = ry ? 0.25f : 0.75f;
    const int cj   = 2 * m;              // local subband col window base (2m..2m+3)
    const size_t off = (size_t)(ty * 64 + orow) * 256 + (size_t)(tx * 64 + 4 * m);

#define EMIT(S, DST)                                                   \
    {                                                                  \
      const float v0 = wA * S[rA][cj + 0] + wB * S[rB][cj + 0];        \
      const float v1 = wA * S[rA][cj + 1] + wB * S[rB][cj + 1];        \
      const float v2 = wA * S[rA][cj + 2] + wB * S[rB][cj + 2];        \
      const float v3 = wA * S[rA][cj + 3] + wB * S[rB][cj + 3];        \
      float4 o;                                                        \
      o.x = 0.25f * v0 + 0.75f * v1;                                   \
      o.y = 0.75f * v1 + 0.25f * v2;                                   \
      o.z = 0.25f * v1 + 0.75f * v2;                                   \
      o.w = 0.75f * v2 + 0.25f * v3;                                   \
      *reinterpret_cast<float4*>((DST) + off) = o;                     \
    }

    EMIT(sLL, oLL)
    EMIT(sLH, oLH)
    EMIT(sHL, oHL)
    EMIT(sHH, oHH)
#undef EMIT
  }
}

extern "C" void kernel_launch(void* const* d_in, const int* in_sizes, int n_in,
                              void* d_out, int out_size, void* d_ws, size_t ws_size,
                              hipStream_t stream) {
  const float* x = (const float*)d_in[0];
  float* out = (float*)d_out;
  dim3 grid(16, 512);   // 4x4 tiles x (8*64 planes)
  haar_dwt_up_kernel<<<grid, 256, 0, stream>>>(x, out);
}

// Round 3
// 120.224 us; speedup vs baseline: 1.1833x; 1.1833x over previous
//
#include <hip/hip_runtime.h>

// Fused Haar DWT (2x2) + 2x bilinear upsample (jax.image.resize half-pixel
// convention == clamped stencil: out[2k]=.25 t[k-1]+.75 t[k], out[2k+1]=.75 t[k]+.25 t[k+1]).
//
// Input  x: [8][64][256][256] f32
// Output: up(ll) [8][64][256][256], then concat([up(lh),up(hl),up(hh)],axis=1) [8][192][256][256]
//
// One block = one 64x64 output tile of one (n,c) plane.
// Step 1: build 34x34 subband halo tiles in LDS (68x68 input patch, float2 loads, cached).
// Step 2: each thread writes 4 float4 rows-of-4 per subband via NONTEMPORAL stores
//         (output is streamed once, never re-read -> don't allocate in L2/L3;
//          keeps L3 free for the input halo re-reads).

typedef float f32x4 __attribute__((ext_vector_type(4)));

__global__ __launch_bounds__(256) void haar_dwt_up_kernel(
    const float* __restrict__ x, float* __restrict__ out)
{
  const int plane = blockIdx.y;       // n*64 + c, 0..511
  const int ty = blockIdx.x >> 2;     // 4x4 tiles of 64x64
  const int tx = blockIdx.x & 3;
  const int tid = threadIdx.x;

  __shared__ float sLL[34][36];
  __shared__ float sLH[34][36];
  __shared__ float sHL[34][36];
  __shared__ float sHH[34][36];

  const float* __restrict__ xp = x + (size_t)plane * 65536u;
  const int kY0 = ty * 32 - 1;        // subband-space tile origin (with -1 halo)
  const int kX0 = tx * 32 - 1;

  // ---- Step 1: subband tiles into LDS ----
  for (int cidx = tid; cidx < 34 * 34; cidx += 256) {
    const int i  = cidx / 34;
    const int jj = cidx - i * 34;
    int k = kY0 + i;  k = k < 0 ? 0 : (k > 127 ? 127 : k);
    int j = kX0 + jj; j = j < 0 ? 0 : (j > 127 ? 127 : j);
    const float2 r0 = *reinterpret_cast<const float2*>(xp + (size_t)(2 * k) * 256 + 2 * j);
    const float2 r1 = *reinterpret_cast<const float2*>(xp + (size_t)(2 * k + 1) * 256 + 2 * j);
    const float a = r0.x, b = r0.y, c = r1.x, d = r1.y;
    sLL[i][jj] = 0.5f * (a + b + c + d);
    sLH[i][jj] = 0.5f * (c + d - a - b);
    sHL[i][jj] = 0.5f * (b + d - a - c);
    sHH[i][jj] = 0.5f * (a + d - b - c);
  }
  __syncthreads();

  // ---- Step 2: bilinear 2x upsample from LDS, 4 subbands, nt stores ----
  const int n = plane >> 6;
  const int c = plane & 63;
  float* __restrict__ oLL = out + (size_t)plane * 65536u;
  float* __restrict__ oLH = out + 33554432u + (size_t)(n * 192 + c) * 65536u;
  float* __restrict__ oHL = oLH + (size_t)64 * 65536u;
  float* __restrict__ oHH = oLH + (size_t)128 * 65536u;

#pragma unroll
  for (int it = 0; it < 4; ++it) {
    const int p    = tid + it * 256;     // 0..1023 float4 slots in 64x64 tile
    const int orow = p >> 4;             // 16 float4s per output row
    const int m    = p & 15;
    const int li   = (orow >> 1) + 1;    // local subband row (halo offset +1)
    const int ry   = orow & 1;
    const int rA   = ry ? li     : li - 1;
    const int rB   = ry ? li + 1 : li;
    const float wA = ry ? 0.75f : 0.25f;
    const float wB = ry ? 0.25f : 0.75f;
    const int cj   = 2 * m;              // local subband col window base (2m..2m+3)
    const size_t off = (size_t)(ty * 64 + orow) * 256 + (size_t)(tx * 64 + 4 * m);

#define EMIT(S, DST)                                                   \
    {                                                                  \
      const float v0 = wA * S[rA][cj + 0] + wB * S[rB][cj + 0];        \
      const float v1 = wA * S[rA][cj + 1] + wB * S[rB][cj + 1];        \
      const float v2 = wA * S[rA][cj + 2] + wB * S[rB][cj + 2];        \
      const float v3 = wA * S[rA][cj + 3] + wB * S[rB][cj + 3];        \
      f32x4 o;                                                         \
      o.x = 0.25f * v0 + 0.75f * v1;                                   \
      o.y = 0.75f * v1 + 0.25f * v2;                                   \
      o.z = 0.25f * v1 + 0.75f * v2;                                   \
      o.w = 0.75f * v2 + 0.25f * v3;                                   \
      __builtin_nontemporal_store(o, reinterpret_cast<f32x4*>((DST) + off)); \
    }

    EMIT(sLL, oLL)
    EMIT(sLH, oLH)
    EMIT(sHL, oHL)
    EMIT(sHH, oHH)
#undef EMIT
  }
}

extern "C" void kernel_launch(void* const* d_in, const int* in_sizes, int n_in,
                              void* d_out, int out_size, void* d_ws, size_t ws_size,
                              hipStream_t stream) {
  const float* x = (const float*)d_in[0];
  float* out = (float*)d_out;
  dim3 grid(16, 512);   // 4x4 tiles x (8*64 planes)
  haar_dwt_up_kernel<<<grid, 256, 0, stream>>>(x, out);
}